// Round 4
// baseline (165.457 us; speedup 1.0000x reference)
//
#include <hip/hip_runtime.h>

#define GAMMA 0.1f
#define MIN_R 0.1f

// Counting-sort-by-range parameters
#define NR 1024                 // nodes per range (power of 2)
#define LOG_NR 10
#define S3 (3 * NR)             // floats per accumulator (12 KB)
#define NB 512                  // blocks for count/scatter kernels
#define THR_AC 256              // threads for count/scatter
#define THR_D 256               // threads for process kernel
#define RMAX 128                // max ranges supported (n_nodes <= 131072)
#define BPR 12                  // blocks per range in process phase

// scatter LDS-staging batch
#define SC_BS 4096              // edges per batch (payload 16 KB)
#define SC_EPT (SC_BS / THR_AC) // 16 edges per thread per batch

// native clang vector type (HIP's uint4 is a class; nontemporal builtin rejects it)
typedef unsigned int u32x4 __attribute__((ext_vector_type(4)));

// ---------------- phase A: per-block range histogram -------------------------
__global__ __launch_bounds__(THR_AC) void count_kernel(
    const int* __restrict__ dst, unsigned* __restrict__ counts,
    int n_edges, int epb, int R)
{
    __shared__ unsigned hist[RMAX];
    const int b = blockIdx.x, t = threadIdx.x;
    if (t < RMAX) hist[t] = 0;
    __syncthreads();
    const int s0 = b * epb;
    const int s1 = min(s0 + epb, n_edges);
    for (int base = s0 + t * 4; base < s1; base += THR_AC * 4) {
        if (base + 3 < s1) {
            int4 d4 = *(const int4*)(dst + base);
            atomicAdd(&hist[(unsigned)d4.x >> LOG_NR], 1u);
            atomicAdd(&hist[(unsigned)d4.y >> LOG_NR], 1u);
            atomicAdd(&hist[(unsigned)d4.z >> LOG_NR], 1u);
            atomicAdd(&hist[(unsigned)d4.w >> LOG_NR], 1u);
        } else {
            for (int e = base; e < s1; ++e)
                atomicAdd(&hist[(unsigned)dst[e] >> LOG_NR], 1u);
        }
    }
    __syncthreads();
    if (t < R) counts[b * R + t] = hist[t];
}

// ---------------- phase B1: per-bin exclusive scan over blocks ---------------
__global__ __launch_bounds__(NB) void scan_blocks_kernel(
    const unsigned* __restrict__ counts, unsigned* __restrict__ bases,
    unsigned* __restrict__ totals, int R)
{
    __shared__ unsigned s[NB];
    const int r = blockIdx.x, t = threadIdx.x;
    unsigned orig = counts[t * R + r];
    s[t] = orig;
    __syncthreads();
    for (int d = 1; d < NB; d <<= 1) {
        unsigned v = (t >= d) ? s[t - d] : 0u;
        __syncthreads();
        s[t] += v;
        __syncthreads();
    }
    bases[t * R + r] = s[t] - orig;           // exclusive
    if (t == NB - 1) totals[r] = s[t];
}

// ---------------- phase B2: exclusive scan over bins -------------------------
__global__ void scan_bins_kernel(const unsigned* __restrict__ totals,
                                 unsigned* __restrict__ offsets, int R)
{
    __shared__ unsigned tot[RMAX];
    const int t = threadIdx.x;
    if (t < R) tot[t] = totals[t];
    __syncthreads();
    if (t == 0) {
        unsigned off = 0;
        for (int r = 0; r < R; ++r) { offsets[r] = off; off += tot[r]; }
        offsets[R] = off;
    }
}

// ---------------- phase C: LDS-staged scatter (coalesced full-line writes) ---
__global__ __launch_bounds__(THR_AC) void scatter_kernel(
    const int* __restrict__ src, const int* __restrict__ dst,
    const unsigned* __restrict__ bases, const unsigned* __restrict__ offsets,
    unsigned* __restrict__ pk, int n_edges, int epb, int R)
{
    __shared__ unsigned payload[SC_BS];       // 16 KB
    __shared__ unsigned char binof[SC_BS];    // 4 KB
    __shared__ unsigned hist[RMAX], loff[RMAX], lcur[RMAX], gcur[RMAX];
    const int b = blockIdx.x, t = threadIdx.x;
    if (t < RMAX) {
        unsigned g = 0;
        if (t < R) g = offsets[t] + bases[b * R + t];
        gcur[t] = g;
    }
    const int s0 = b * epb;
    const int s1 = min(s0 + epb, n_edges);

    for (int bs = s0; bs < s1; bs += SC_BS) {
        const int n = min(SC_BS, s1 - bs);
        const int lim = bs + n;
        if (t < RMAX) hist[t] = 0;
        __syncthreads();

        // ---- pass 1: per-batch histogram ----
        {
            const int base = bs + t * SC_EPT;
            #pragma unroll
            for (int k = 0; k < SC_EPT; k += 4) {
                int e = base + k;
                if (e + 3 < lim) {
                    int4 d4 = *(const int4*)(dst + e);
                    atomicAdd(&hist[(unsigned)d4.x >> LOG_NR], 1u);
                    atomicAdd(&hist[(unsigned)d4.y >> LOG_NR], 1u);
                    atomicAdd(&hist[(unsigned)d4.z >> LOG_NR], 1u);
                    atomicAdd(&hist[(unsigned)d4.w >> LOG_NR], 1u);
                } else {
                    for (int q = e; q < lim; ++q)
                        atomicAdd(&hist[(unsigned)dst[q] >> LOG_NR], 1u);
                    break;
                }
            }
        }
        __syncthreads();

        // ---- exclusive scan over RMAX bins (Hillis-Steele) ----
        if (t < RMAX) loff[t] = hist[t];
        __syncthreads();
        for (int d = 1; d < RMAX; d <<= 1) {
            unsigned a = 0;
            if (t < RMAX && t >= d) a = loff[t - d];
            __syncthreads();
            if (t < RMAX) loff[t] += a;
            __syncthreads();
        }
        {
            unsigned ex = 0;
            if (t < RMAX) ex = loff[t] - hist[t];
            __syncthreads();
            if (t < RMAX) { loff[t] = ex; lcur[t] = ex; }
        }
        __syncthreads();

        // ---- pass 2: deposit into LDS (sorted by bin) ----
        {
            const int base = bs + t * SC_EPT;
            #pragma unroll
            for (int k = 0; k < SC_EPT; k += 4) {
                int e = base + k;
                if (e + 3 < lim) {
                    int4 d4 = *(const int4*)(dst + e);
                    int4 s4 = *(const int4*)(src + e);
                    #pragma unroll
                    for (int q = 0; q < 4; ++q) {
                        unsigned d = (unsigned)((q == 0) ? d4.x : (q == 1) ? d4.y : (q == 2) ? d4.z : d4.w);
                        unsigned sv = (unsigned)((q == 0) ? s4.x : (q == 1) ? s4.y : (q == 2) ? s4.z : s4.w);
                        unsigned r = d >> LOG_NR;
                        unsigned w = ((d & (NR - 1)) << 17) | sv;
                        unsigned slot = atomicAdd(&lcur[r], 1u);
                        payload[slot] = w;
                        binof[slot] = (unsigned char)r;
                    }
                } else {
                    for (int q = e; q < lim; ++q) {
                        unsigned d = (unsigned)dst[q];
                        unsigned sv = (unsigned)src[q];
                        unsigned r = d >> LOG_NR;
                        unsigned w = ((d & (NR - 1)) << 17) | sv;
                        unsigned slot = atomicAdd(&lcur[r], 1u);
                        payload[slot] = w;
                        binof[slot] = (unsigned char)r;
                    }
                    break;
                }
            }
        }
        __syncthreads();

        // ---- flush: consecutive LDS slots -> consecutive global positions ----
        for (int j = t; j < n; j += THR_AC) {
            unsigned w = payload[j];
            unsigned r = binof[j];
            pk[gcur[r] + ((unsigned)j - loff[r])] = w;
        }
        __syncthreads();
        if (t < RMAX) gcur[t] += hist[t];   // same-index per thread; safe
    }
}

// ---------------- prep: pack x into padded float4 ----------------------------
__global__ void prep_xp_kernel(const float* __restrict__ x,
                               float4* __restrict__ xp, int n_nodes)
{
    int i = blockIdx.x * blockDim.x + threadIdx.x;
    if (i < n_nodes)
        xp[i] = make_float4(x[3 * i + 0], x[3 * i + 1], x[3 * i + 2], 0.0f);
}

// ---------------- phase D: dense per-range LJ accumulate ---------------------
__device__ __forceinline__ void lj_force3(float dx, float dy, float dz,
                                          float& fx, float& fy, float& fz)
{
    float r2 = dx * dx + dy * dy + dz * dz;
    float rr = sqrtf(r2);
    float inv_norm = 1.0f / fmaxf(rr, 1e-12f);
    float rc = fmaxf(rr, MIN_R);
    float s1 = 1.0f / rc;                 // RC = 1
    float s2 = s1 * s1;
    float s6 = s2 * s2 * s2;
    float F = 4.0f * s6 * (12.0f * s6 - 6.0f) * s1;
    float sc = F * inv_norm;
    fx = sc * dx; fy = sc * dy; fz = sc * dz;
}

__device__ __forceinline__ void do_edge(unsigned p,
                                        const float4* __restrict__ xp,
                                        const float4* xr4, float* acc)
{
    int s = (int)(p & 0x1FFFFu);
    int u = (int)(p >> 17);
    float4 xs = xp[s];
    float4 xu = xr4[u];
    float dx = xu.x - xs.x;
    float dy = xu.y - xs.y;
    float dz = xu.z - xs.z;
    float fx, fy, fz;
    lj_force3(dx, dy, dz, fx, fy, fz);
    unsafeAtomicAdd(&acc[3 * u + 0], fx);
    unsafeAtomicAdd(&acc[3 * u + 1], fy);
    unsafeAtomicAdd(&acc[3 * u + 2], fz);
}

__global__ __launch_bounds__(THR_D) void process_kernel(
    const float4* __restrict__ xp, const unsigned* __restrict__ pk,
    const unsigned* __restrict__ offsets, float* __restrict__ slabs,
    int n_nodes, int bpr)
{
    __shared__ __align__(16) float acc[S3];
    __shared__ __align__(16) float4 xr4[NR];
    const int b = blockIdx.x, r = blockIdx.y, t = threadIdx.x;
    const int node0 = r << LOG_NR;
    for (int i = t; i < S3; i += THR_D) acc[i] = 0.0f;
    for (int i = t; i < NR; i += THR_D) {
        int g = node0 + i;
        xr4[i] = (g < n_nodes) ? xp[g] : make_float4(0.f, 0.f, 0.f, 0.f);
    }
    __syncthreads();

    const int e0 = (int)offsets[r];
    const int e1 = (int)offsets[r + 1];
    const int cnt = e1 - e0;
    const int ebp = (cnt + bpr - 1) / bpr;
    const int st = e0 + b * ebp;
    const int en = min(st + ebp, e1);

    if (st < en) {
        // scalar head to reach 16B alignment of pk+index
        const int st_al = min((st + 3) & ~3, en);
        if (t < st_al - st) do_edge(pk[st + t], xp, xr4, acc);
        // aligned uint4 main loop
        const int en4 = st_al + ((en - st_al) & ~3);
        for (int i = st_al + 4 * t; i + 3 < en4; i += 4 * THR_D) {
            u32x4 p4 = __builtin_nontemporal_load((const u32x4*)(pk + i));
            unsigned pw[4] = {p4.x, p4.y, p4.z, p4.w};
            int sI[4], uI[4];
            float4 xs[4];
            #pragma unroll
            for (int k = 0; k < 4; ++k) {
                sI[k] = (int)(pw[k] & 0x1FFFFu);
                uI[k] = (int)(pw[k] >> 17);
            }
            #pragma unroll
            for (int k = 0; k < 4; ++k) xs[k] = xp[sI[k]];
            #pragma unroll
            for (int k = 0; k < 4; ++k) {
                float4 xu = xr4[uI[k]];
                float dx = xu.x - xs[k].x;
                float dy = xu.y - xs[k].y;
                float dz = xu.z - xs[k].z;
                float fx, fy, fz;
                lj_force3(dx, dy, dz, fx, fy, fz);
                unsafeAtomicAdd(&acc[3 * uI[k] + 0], fx);
                unsafeAtomicAdd(&acc[3 * uI[k] + 1], fy);
                unsafeAtomicAdd(&acc[3 * uI[k] + 2], fz);
            }
        }
        // scalar tail
        if (t < en - en4) do_edge(pk[en4 + t], xp, xr4, acc);
    }
    __syncthreads();

    // epilogue: disjoint slab store (coalesced, no atomics)
    float* slab = slabs + (size_t)(r * bpr + b) * S3;
    const float4* a4 = (const float4*)acc;
    float4* s4 = (float4*)slab;
    for (int i = t; i < S3 / 4; i += THR_D) s4[i] = a4[i];
}

// ---------------- phase E: merge slabs + fuse -gamma*v -----------------------
__global__ void merge_kernel(const float* __restrict__ slabs,
                             const float* __restrict__ v,
                             float* __restrict__ out,
                             int n_out, int bpr)
{
    int t = blockIdx.x * blockDim.x + threadIdx.x;
    int g = t * 4;
    if (g + 3 < n_out) {
        int r = g / S3;
        int j = g - r * S3;
        const float4* base = (const float4*)(slabs + (size_t)r * bpr * S3 + j);
        float4 sum = make_float4(0.f, 0.f, 0.f, 0.f);
        for (int b = 0; b < bpr; ++b) {
            float4 p = base[(size_t)b * (S3 / 4)];
            sum.x += p.x; sum.y += p.y; sum.z += p.z; sum.w += p.w;
        }
        float4 vg = *(const float4*)(v + g);
        float4 o;
        o.x = sum.x - GAMMA * vg.x;
        o.y = sum.y - GAMMA * vg.y;
        o.z = sum.z - GAMMA * vg.z;
        o.w = sum.w - GAMMA * vg.w;
        *(float4*)(out + g) = o;
    } else {
        for (; g < n_out; ++g) {
            int r = g / S3;
            int j = g - r * S3;
            const float* base = slabs + (size_t)r * bpr * S3 + j;
            float sum = 0.0f;
            for (int b = 0; b < bpr; ++b) sum += base[(size_t)b * S3];
            out[g] = sum - GAMMA * v[g];
        }
    }
}

// ---------------- fallback path (no ws / too many nodes) ---------------------
__global__ void init_out_kernel(const float* __restrict__ v,
                                float* __restrict__ out, int n) {
    int i = blockIdx.x * blockDim.x + threadIdx.x;
    if (i < n) out[i] = -GAMMA * v[i];
}

__global__ void edge_atomic_kernel(const float* __restrict__ x,
                                   const int* __restrict__ src,
                                   const int* __restrict__ dst,
                                   float* __restrict__ out, int n_edges) {
    int t = blockIdx.x * blockDim.x + threadIdx.x;
    int e = t;
    if (e < n_edges) {
        int s = src[e], d = dst[e];
        float dx = x[3 * d + 0] - x[3 * s + 0];
        float dy = x[3 * d + 1] - x[3 * s + 1];
        float dz = x[3 * d + 2] - x[3 * s + 2];
        float fx, fy, fz;
        lj_force3(dx, dy, dz, fx, fy, fz);
        unsafeAtomicAdd(&out[3 * d + 0], fx);
        unsafeAtomicAdd(&out[3 * d + 1], fy);
        unsafeAtomicAdd(&out[3 * d + 2], fz);
    }
}

extern "C" void kernel_launch(void* const* d_in, const int* in_sizes, int n_in,
                              void* d_out, int out_size, void* d_ws, size_t ws_size,
                              hipStream_t stream) {
    const float* x   = (const float*)d_in[0];
    const float* v   = (const float*)d_in[1];
    const int*   src = (const int*)d_in[2];
    const int*   dst = (const int*)d_in[3];
    float* out = (float*)d_out;

    const int n_out = out_size;
    const int n_nodes = out_size / 3;
    const int n_edges = in_sizes[2];
    const int R = (n_nodes + NR - 1) / NR;

    // ws layout (u32 units for tables)
    const size_t counts_off  = 0;                       // NB*R
    const size_t bases_off   = (size_t)NB * R;          // NB*R
    const size_t totals_off  = 2 * (size_t)NB * R;      // R
    const size_t offsets_off = totals_off + R;          // R+1
    const size_t tables_end  = offsets_off + R + 1;
    const size_t pk_byte_off = ((tables_end * 4) + 63) & ~(size_t)63;
    const size_t xp_byte_off = ((pk_byte_off + (size_t)n_edges * 4) + 63) & ~(size_t)63;
    const size_t slab_byte_off = ((xp_byte_off + (size_t)n_nodes * 16) + 63) & ~(size_t)63;

    int bpr = 0;
    if (n_nodes <= (1 << 17) && R <= RMAX) {
        for (int cand : {BPR, 8, 4}) {
            size_t need = slab_byte_off + (size_t)R * cand * S3 * sizeof(float);
            if (need <= ws_size) { bpr = cand; break; }
        }
    }

    const int blk = 256;
    if (bpr > 0) {
        unsigned* tables  = (unsigned*)d_ws;
        unsigned* counts  = tables + counts_off;
        unsigned* bases   = tables + bases_off;
        unsigned* totals  = tables + totals_off;
        unsigned* offsets = tables + offsets_off;
        unsigned* pk      = (unsigned*)((char*)d_ws + pk_byte_off);
        float4*   xp      = (float4*)((char*)d_ws + xp_byte_off);
        float*    slabs   = (float*)((char*)d_ws + slab_byte_off);

        int epb = ((n_edges + NB - 1) / NB + 3) & ~3;

        prep_xp_kernel<<<(n_nodes + blk - 1) / blk, blk, 0, stream>>>(x, xp, n_nodes);
        count_kernel<<<NB, THR_AC, 0, stream>>>(dst, counts, n_edges, epb, R);
        scan_blocks_kernel<<<R, NB, 0, stream>>>(counts, bases, totals, R);
        scan_bins_kernel<<<1, RMAX, 0, stream>>>(totals, offsets, R);
        scatter_kernel<<<NB, THR_AC, 0, stream>>>(src, dst, bases, offsets, pk,
                                                  n_edges, epb, R);
        dim3 gridD(bpr, R);
        process_kernel<<<gridD, THR_D, 0, stream>>>(xp, pk, offsets, slabs,
                                                    n_nodes, bpr);
        int n4 = (n_out + 3) / 4;
        merge_kernel<<<(n4 + 255) / 256, 256, 0, stream>>>(slabs, v, out,
                                                           n_out, bpr);
    } else {
        init_out_kernel<<<(n_out + blk - 1) / blk, blk, 0, stream>>>(v, out, n_out);
        edge_atomic_kernel<<<(n_edges + blk - 1) / blk, blk, 0, stream>>>(
            x, src, dst, out, n_edges);
    }
}